// Round 4
// baseline (391.449 us; speedup 1.0000x reference)
//
#include <hip/hip_runtime.h>
#include <hip/hip_fp16.h>

// GCN: out = dinv ⊙ ( A_sum ( dinv ⊙ (x@W) ) ) + b, A_sum includes self-loop.
// CSR (by dst) built on-device via bucketed multi-split (LDS atomics on hot path).
// Aggregation: fp16 gather operand stored CHUNK-MAJOR [4][N][32] so each of 4
// column-passes has a 3.2MB working set (fits 4MB per-XCD L2). fp32 accumulate.

#define NBUK_MAX 512  // buckets of 128 nodes; N=50000 -> 391 buckets

__global__ __launch_bounds__(256) void k_bhist(const int* __restrict__ dst, int E, int nbuk,
                                               int* __restrict__ bcount) {
    __shared__ int h[NBUK_MAX];
    int tid = threadIdx.x;
    for (int i = tid; i < nbuk; i += 256) h[i] = 0;
    __syncthreads();
    int s0 = blockIdx.x * 4096;
#pragma unroll
    for (int i = 0; i < 16; i++) {
        int e = s0 + i * 256 + tid;
        if (e < E) atomicAdd(&h[dst[e] >> 7], 1);
    }
    __syncthreads();
    for (int i = tid; i < nbuk; i += 256)
        if (h[i]) atomicAdd(&bcount[i], h[i]);
}

__global__ __launch_bounds__(512) void k_bscan(const int* __restrict__ bcount, int nb,
                                               int* __restrict__ bbase, int* __restrict__ bcur) {
    __shared__ int s[512];
    int tid = threadIdx.x;
    int v = (tid < nb) ? bcount[tid] : 0;
    s[tid] = v;
    __syncthreads();
    for (int off = 1; off < 512; off <<= 1) {
        int t = (tid >= off) ? s[tid - off] : 0;
        __syncthreads();
        s[tid] += t;
        __syncthreads();
    }
    if (tid < nb) {
        int excl = s[tid] - v;
        bbase[tid] = excl;
        bcur[tid] = excl;
        if (tid == nb - 1) bbase[nb] = s[tid];
    }
}

__global__ __launch_bounds__(256) void k_passA(const int* __restrict__ src,
                                               const int* __restrict__ dst, int E, int nbuk,
                                               int* __restrict__ bcur,
                                               unsigned* __restrict__ bbuf) {
    __shared__ int h[NBUK_MAX];
    __shared__ int base[NBUK_MAX];
    __shared__ int lcur[NBUK_MAX];
    int tid = threadIdx.x;
    for (int i = tid; i < nbuk; i += 256) h[i] = 0;
    __syncthreads();
    int s0 = blockIdx.x * 4096;
#pragma unroll
    for (int i = 0; i < 16; i++) {
        int e = s0 + i * 256 + tid;
        if (e < E) atomicAdd(&h[dst[e] >> 7], 1);
    }
    __syncthreads();
    for (int i = tid; i < nbuk; i += 256) {
        int c = h[i];
        base[i] = c ? atomicAdd(&bcur[i], c) : 0;
        lcur[i] = 0;
    }
    __syncthreads();
#pragma unroll
    for (int i = 0; i < 16; i++) {
        int e = s0 + i * 256 + tid;
        if (e < E) {
            int d = dst[e];
            int b = d >> 7;
            int idx = atomicAdd(&lcur[b], 1);
            bbuf[base[b] + idx] = ((unsigned)d << 16) | (unsigned)src[e];
        }
    }
}

__global__ __launch_bounds__(256) void k_passB(const unsigned* __restrict__ bbuf,
                                               const int* __restrict__ bbase, int N,
                                               int* __restrict__ row_ptr,
                                               float* __restrict__ dinv,
                                               unsigned short* __restrict__ sorted) {
    __shared__ int h[128], sc[128], lc[128];
    int b = blockIdx.x, tid = threadIdx.x;
    int node0 = b << 7;
    int ncnt = min(128, N - node0);
    int s = bbase[b], e = bbase[b + 1];
    if (tid < 128) h[tid] = 0;
    __syncthreads();
    for (int i = s + tid; i < e; i += 256) atomicAdd(&h[(bbuf[i] >> 16) & 127], 1);
    __syncthreads();
    if (tid < 128) sc[tid] = h[tid];
    __syncthreads();
    for (int off = 1; off < 128; off <<= 1) {
        int t = 0;
        if (tid < 128 && tid >= off) t = sc[tid - off];
        __syncthreads();
        if (tid < 128) sc[tid] += t;
        __syncthreads();
    }
    if (tid < ncnt) {
        int excl = sc[tid] - h[tid];
        row_ptr[node0 + tid] = s + excl;
        dinv[node0 + tid] = rsqrtf((float)(h[tid] + 1));  // +1 self-loop
        lc[tid] = excl;
    }
    if (b == gridDim.x - 1 && tid == 0) row_ptr[N] = e;
    __syncthreads();
    for (int i = s + tid; i < e; i += 256) {
        unsigned p = bbuf[i];
        int nl = (p >> 16) & 127;
        int idx = atomicAdd(&lc[nl], 1);
        sorted[s + idx] = (unsigned short)(p & 0xffffu);
    }
}

// hs[(c>>5)][n][c&31] = (half) dinv[n] * sum_k in[n][k]*W[k][c]  (chunk-major fp16 out)
__global__ __launch_bounds__(256) void k_gemm_scale_h(const float* __restrict__ in,
                                                      const float* __restrict__ W,
                                                      const float* __restrict__ dinv, int N,
                                                      __half* __restrict__ out) {
    __shared__ float Ws[32][128];
    __shared__ float Xs[32][64];
    int tid = threadIdx.x;
    int row0 = blockIdx.x * 64;
    int tc = tid & 15;   // 16 col groups x 8 cols
    int tr = tid >> 4;   // 16 row groups x 4 rows
    float acc[4][8];
#pragma unroll
    for (int i = 0; i < 4; i++)
#pragma unroll
        for (int j = 0; j < 8; j++) acc[i][j] = 0.f;

    for (int k0 = 0; k0 < 128; k0 += 32) {
#pragma unroll
        for (int j = 0; j < 4; j++) {  // stage W chunk: 32x128 = 1024 float4
            int u = tid + j * 256;
            int kk = u >> 5, c4 = u & 31;
            *(float4*)&Ws[kk][c4 * 4] = *(const float4*)&W[(k0 + kk) * 128 + c4 * 4];
        }
#pragma unroll
        for (int j = 0; j < 2; j++) {  // stage X chunk transposed: 64 rows x 32 k
            int u = tid + j * 256;     // 512 float4 units
            int r = u >> 3, kq = u & 7;
            int row = row0 + r;
            if (row > N - 1) row = N - 1;
            float4 v = *(const float4*)&in[(size_t)row * 128 + k0 + kq * 4];
            Xs[kq * 4 + 0][r] = v.x;
            Xs[kq * 4 + 1][r] = v.y;
            Xs[kq * 4 + 2][r] = v.z;
            Xs[kq * 4 + 3][r] = v.w;
        }
        __syncthreads();
#pragma unroll 8
        for (int kk = 0; kk < 32; kk++) {
            float4 xv = *(const float4*)&Xs[kk][tr * 4];
            float4 wa = *(const float4*)&Ws[kk][tc * 8];
            float4 wb = *(const float4*)&Ws[kk][tc * 8 + 4];
            float xr[4] = {xv.x, xv.y, xv.z, xv.w};
            float wc[8] = {wa.x, wa.y, wa.z, wa.w, wb.x, wb.y, wb.z, wb.w};
#pragma unroll
            for (int i = 0; i < 4; i++)
#pragma unroll
                for (int j = 0; j < 8; j++) acc[i][j] += xr[i] * wc[j];
        }
        __syncthreads();
    }
#pragma unroll
    for (int i = 0; i < 4; i++) {
        int row = row0 + tr * 4 + i;
        if (row < N) {
            float di = dinv[row];
            union {
                uint4 u;
                __half h[8];
            } pk;
#pragma unroll
            for (int j = 0; j < 8; j++) pk.h[j] = __float2half_rn(di * acc[i][j]);
            // chunk-major: chunk = tc>>2, col-in-chunk = (tc&3)*8
            *(uint4*)&out[((size_t)(tc >> 2) * N + row) * 32 + (tc & 3) * 8] = pk.u;
        }
    }
}

// one wave per node per 32-col chunk; 4 lane-groups of 16 process 4 edges/iter.
// hs is the chunk base [N][32] fp16; out is [N][128] fp32 at col offset c0.
__global__ __launch_bounds__(256) void k_agg32(const __half* __restrict__ hs,
                                               const int* __restrict__ row_ptr,
                                               const unsigned short* __restrict__ ss,
                                               const float* __restrict__ dinv,
                                               const float* __restrict__ bias, int N,
                                               int c0, int do_relu,
                                               float* __restrict__ out) {
    int wid = threadIdx.x >> 6;
    int lane = threadIdx.x & 63;
    int node = blockIdx.x * 4 + wid;
    if (node >= N) return;
    int g = lane >> 4;   // edge group 0..3
    int cl = lane & 15;  // col-pair within chunk
    const __half2* hp = (const __half2*)hs;  // row stride 16 half2
    float2 acc = {0.f, 0.f};
    {
        float2 sv = __half22float2(hp[(size_t)node * 16 + cl]);  // self-loop term
        if (g == 0) acc = sv;
    }
    int s = row_ptr[node], e = row_ptr[node + 1];
    for (int i = s; i < e; i += 8) {
        int i0 = i + g, i1 = i + 4 + g;
        if (i1 < e) {
            int r0 = ss[i0], r1 = ss[i1];
            float2 v0 = __half22float2(hp[(size_t)r0 * 16 + cl]);
            float2 v1 = __half22float2(hp[(size_t)r1 * 16 + cl]);
            acc.x += v0.x + v1.x;
            acc.y += v0.y + v1.y;
        } else if (i0 < e) {
            int r0 = ss[i0];
            float2 v0 = __half22float2(hp[(size_t)r0 * 16 + cl]);
            acc.x += v0.x;
            acc.y += v0.y;
        }
    }
    // reduce across the 4 edge-groups (same cl)
    acc.x += __shfl_xor(acc.x, 16);
    acc.y += __shfl_xor(acc.y, 16);
    acc.x += __shfl_xor(acc.x, 32);
    acc.y += __shfl_xor(acc.y, 32);
    if (g == 0) {
        float di = dinv[node];
        float2 b = *(const float2*)&bias[c0 + cl * 2];
        float ox = di * acc.x + b.x;
        float oy = di * acc.y + b.y;
        if (do_relu) {
            ox = fmaxf(ox, 0.f);
            oy = fmaxf(oy, 0.f);
        }
        *(float2*)&out[(size_t)node * 128 + c0 + cl * 2] = {ox, oy};
    }
}

// heads: ths[n][j] = dinv[n] * sum_k h[n][k] * Wcat[k][j], Wcat = [W_age|W_sex|W_eth]
__global__ __launch_bounds__(256) void k_headgemm(const float* __restrict__ h,
                                                  const float* __restrict__ Wa,
                                                  const float* __restrict__ Wsx,
                                                  const float* __restrict__ We,
                                                  const float* __restrict__ dinv, int N,
                                                  float* __restrict__ ths) {
    __shared__ float Ws8[128][8];
    int tid = threadIdx.x;
#pragma unroll
    for (int j = 0; j < 4; j++) {
        int u = tid + j * 256;  // 1024 entries
        int k = u >> 3, c = u & 7;
        float v;
        if (c < 3) v = Wa[k * 3 + c];
        else if (c < 5) v = Wsx[k * 2 + (c - 3)];
        else v = We[k * 3 + (c - 5)];
        Ws8[k][c] = v;
    }
    __syncthreads();
    int node = blockIdx.x * 32 + (tid >> 3);
    int col = tid & 7;
    if (node >= N) return;
    const float* hr = &h[(size_t)node * 128];
    float acc = 0.f;
#pragma unroll 4
    for (int k = 0; k < 128; k += 4) {
        float4 hv = *(const float4*)&hr[k];
        acc += hv.x * Ws8[k][col] + hv.y * Ws8[k + 1][col] + hv.z * Ws8[k + 2][col] +
               hv.w * Ws8[k + 3][col];
    }
    ths[(size_t)node * 8 + col] = dinv[node] * acc;
}

__global__ __launch_bounds__(256) void k_agg8(const float* __restrict__ ths,
                                              const int* __restrict__ row_ptr,
                                              const unsigned short* __restrict__ ss,
                                              const float* __restrict__ dinv,
                                              const float* __restrict__ ba,
                                              const float* __restrict__ bs,
                                              const float* __restrict__ be, int N,
                                              float* __restrict__ outp) {
    int tid = threadIdx.x;
    int node = blockIdx.x * 32 + (tid >> 3);
    int j = tid & 7;
    if (node >= N) return;
    float acc = ths[(size_t)node * 8 + j];  // self
    int s = row_ptr[node], e = row_ptr[node + 1];
    for (int i = s; i < e; i++) {
        int sc = ss[i];
        acc += ths[(size_t)sc * 8 + j];
    }
    float bias = (j < 3) ? ba[j] : ((j < 5) ? bs[j - 3] : be[j - 5]);
    float v = dinv[node] * acc + bias;
    if (j < 3) outp[(size_t)node * 3 + j] = v;
    else if (j < 5) outp[(size_t)N * 3 + (size_t)node * 2 + (j - 3)] = v;
    else outp[(size_t)N * 5 + (size_t)node * 3 + (j - 5)] = v;
}

extern "C" void kernel_launch(void* const* d_in, const int* in_sizes, int n_in,
                              void* d_out, int out_size, void* d_ws, size_t ws_size,
                              hipStream_t stream) {
    const float* x = (const float*)d_in[0];
    const int* edge = (const int*)d_in[1];
    const float* W1 = (const float*)d_in[2];
    const float* b1 = (const float*)d_in[3];
    const float* W2 = (const float*)d_in[4];
    const float* b2 = (const float*)d_in[5];
    const float* Wa = (const float*)d_in[6];
    const float* ba = (const float*)d_in[7];
    const float* Wsx = (const float*)d_in[8];
    const float* bs = (const float*)d_in[9];
    const float* We = (const float*)d_in[10];
    const float* be = (const float*)d_in[11];

    int N = in_sizes[0] / 128;
    int E = in_sizes[1] / 2;
    const int* srcp = edge;
    const int* dstp = edge + E;
    int nbuk = (N + 127) >> 7;

    char* ws = (char*)d_ws;
    size_t off = 0;
    auto alloc = [&](size_t bytes) -> char* {
        char* p = ws + off;
        off += (bytes + 255) & ~(size_t)255;
        return p;
    };
    int* bcount = (int*)alloc((size_t)(nbuk + 1) * 4);
    int* bbase = (int*)alloc((size_t)(nbuk + 1) * 4);
    int* bcur = (int*)alloc((size_t)(nbuk + 1) * 4);
    int* row_ptr = (int*)alloc((size_t)(N + 1) * 4);
    float* dinv = (float*)alloc((size_t)N * 4);
    unsigned* bbuf = (unsigned*)alloc((size_t)E * 4);
    unsigned short* sorted = (unsigned short*)alloc((size_t)E * 2);
    __half* bufH = (__half*)alloc((size_t)N * 128 * 2);  // chunk-major [4][N][32] fp16
    float* bufF = (float*)alloc((size_t)N * 128 * 4);    // fp32 agg output / gemm input
    float* ths = (float*)alloc((size_t)N * 8 * 4);

    int nbT = (E + 4095) / 4096;

    hipMemsetAsync(bcount, 0, (size_t)(nbuk + 1) * 4, stream);
    k_bhist<<<nbT, 256, 0, stream>>>(dstp, E, nbuk, bcount);
    k_bscan<<<1, 512, 0, stream>>>(bcount, nbuk, bbase, bcur);
    k_passA<<<nbT, 256, 0, stream>>>(srcp, dstp, E, nbuk, bcur, bbuf);
    k_passB<<<nbuk, 256, 0, stream>>>(bbuf, bbase, N, row_ptr, dinv, sorted);

    int gb = (N + 63) / 64;
    int ab = (N + 3) / 4;
    k_gemm_scale_h<<<gb, 256, 0, stream>>>(x, W1, dinv, N, bufH);
    for (int p = 0; p < 4; p++)
        k_agg32<<<ab, 256, 0, stream>>>(bufH + (size_t)p * N * 32, row_ptr, sorted, dinv,
                                        b1, N, p * 32, 1, bufF);
    k_gemm_scale_h<<<gb, 256, 0, stream>>>(bufF, W2, dinv, N, bufH);
    for (int p = 0; p < 4; p++)
        k_agg32<<<ab, 256, 0, stream>>>(bufH + (size_t)p * N * 32, row_ptr, sorted, dinv,
                                        b2, N, p * 32, 1, bufF);
    k_headgemm<<<(N + 31) / 32, 256, 0, stream>>>(bufF, Wa, Wsx, We, dinv, N, ths);
    k_agg8<<<(N + 31) / 32, 256, 0, stream>>>(ths, row_ptr, sorted, dinv, ba, bs, be, N,
                                              (float*)d_out);
}

// Round 5
// 278.957 us; speedup vs baseline: 1.4033x; 1.4033x over previous
//
#include <hip/hip_runtime.h>
#include <hip/hip_fp16.h>

// GCN: out = dinv ⊙ ( A_sum ( dinv ⊙ (x@W) ) ) + b, A_sum includes self-loop.
// CSR (by dst) built on-device via bucketed multi-split (LDS atomics on hot path).
// Pull aggregation gathers a row-major fp16 copy of hs; fp32 accumulate.
// 8-deep unrolled gather (MLP), NT loads for the index stream, NT stores for the
// fp32 output stream (keep the 12.8MB gather operand L2-resident).

#define NBUK_MAX 512  // buckets of 128 nodes; N=50000 -> 391 buckets

typedef float vfloat2 __attribute__((ext_vector_type(2)));

__global__ __launch_bounds__(256) void k_bhist(const int* __restrict__ dst, int E, int nbuk,
                                               int* __restrict__ bcount) {
    __shared__ int h[NBUK_MAX];
    int tid = threadIdx.x;
    for (int i = tid; i < nbuk; i += 256) h[i] = 0;
    __syncthreads();
    int s0 = blockIdx.x * 4096;
#pragma unroll
    for (int i = 0; i < 16; i++) {
        int e = s0 + i * 256 + tid;
        if (e < E) atomicAdd(&h[dst[e] >> 7], 1);
    }
    __syncthreads();
    for (int i = tid; i < nbuk; i += 256)
        if (h[i]) atomicAdd(&bcount[i], h[i]);
}

__global__ __launch_bounds__(512) void k_bscan(const int* __restrict__ bcount, int nb,
                                               int* __restrict__ bbase, int* __restrict__ bcur) {
    __shared__ int s[512];
    int tid = threadIdx.x;
    int v = (tid < nb) ? bcount[tid] : 0;
    s[tid] = v;
    __syncthreads();
    for (int off = 1; off < 512; off <<= 1) {
        int t = (tid >= off) ? s[tid - off] : 0;
        __syncthreads();
        s[tid] += t;
        __syncthreads();
    }
    if (tid < nb) {
        int excl = s[tid] - v;
        bbase[tid] = excl;
        bcur[tid] = excl;
        if (tid == nb - 1) bbase[nb] = s[tid];
    }
}

__global__ __launch_bounds__(256) void k_passA(const int* __restrict__ src,
                                               const int* __restrict__ dst, int E, int nbuk,
                                               int* __restrict__ bcur,
                                               unsigned* __restrict__ bbuf) {
    __shared__ int h[NBUK_MAX];
    __shared__ int base[NBUK_MAX];
    __shared__ int lcur[NBUK_MAX];
    int tid = threadIdx.x;
    for (int i = tid; i < nbuk; i += 256) h[i] = 0;
    __syncthreads();
    int s0 = blockIdx.x * 4096;
#pragma unroll
    for (int i = 0; i < 16; i++) {
        int e = s0 + i * 256 + tid;
        if (e < E) atomicAdd(&h[dst[e] >> 7], 1);
    }
    __syncthreads();
    for (int i = tid; i < nbuk; i += 256) {
        int c = h[i];
        base[i] = c ? atomicAdd(&bcur[i], c) : 0;
        lcur[i] = 0;
    }
    __syncthreads();
#pragma unroll
    for (int i = 0; i < 16; i++) {
        int e = s0 + i * 256 + tid;
        if (e < E) {
            int d = dst[e];
            int b = d >> 7;
            int idx = atomicAdd(&lcur[b], 1);
            bbuf[base[b] + idx] = ((unsigned)d << 16) | (unsigned)src[e];
        }
    }
}

__global__ __launch_bounds__(256) void k_passB(const unsigned* __restrict__ bbuf,
                                               const int* __restrict__ bbase, int N,
                                               int* __restrict__ row_ptr,
                                               float* __restrict__ dinv,
                                               unsigned short* __restrict__ sorted) {
    __shared__ int h[128], sc[128], lc[128];
    int b = blockIdx.x, tid = threadIdx.x;
    int node0 = b << 7;
    int ncnt = min(128, N - node0);
    int s = bbase[b], e = bbase[b + 1];
    if (tid < 128) h[tid] = 0;
    __syncthreads();
    for (int i = s + tid; i < e; i += 256) atomicAdd(&h[(bbuf[i] >> 16) & 127], 1);
    __syncthreads();
    if (tid < 128) sc[tid] = h[tid];
    __syncthreads();
    for (int off = 1; off < 128; off <<= 1) {
        int t = 0;
        if (tid < 128 && tid >= off) t = sc[tid - off];
        __syncthreads();
        if (tid < 128) sc[tid] += t;
        __syncthreads();
    }
    if (tid < ncnt) {
        int excl = sc[tid] - h[tid];
        row_ptr[node0 + tid] = s + excl;
        dinv[node0 + tid] = rsqrtf((float)(h[tid] + 1));  // +1 self-loop
        lc[tid] = excl;
    }
    if (b == gridDim.x - 1 && tid == 0) row_ptr[N] = e;
    __syncthreads();
    for (int i = s + tid; i < e; i += 256) {
        unsigned p = bbuf[i];
        int nl = (p >> 16) & 127;
        int idx = atomicAdd(&lc[nl], 1);
        sorted[s + idx] = (unsigned short)(p & 0xffffu);
    }
}

// out[n][c] = (half) dinv[n] * sum_k in[n][k]*W[k][c]   (N x 128) @ (128 x 128)
__global__ __launch_bounds__(256) void k_gemm_scale_h(const float* __restrict__ in,
                                                      const float* __restrict__ W,
                                                      const float* __restrict__ dinv, int N,
                                                      __half* __restrict__ out) {
    __shared__ float Ws[32][128];
    __shared__ float Xs[32][64];
    int tid = threadIdx.x;
    int row0 = blockIdx.x * 64;
    int tc = tid & 15;   // 16 col groups x 8 cols
    int tr = tid >> 4;   // 16 row groups x 4 rows
    float acc[4][8];
#pragma unroll
    for (int i = 0; i < 4; i++)
#pragma unroll
        for (int j = 0; j < 8; j++) acc[i][j] = 0.f;

    for (int k0 = 0; k0 < 128; k0 += 32) {
#pragma unroll
        for (int j = 0; j < 4; j++) {  // stage W chunk: 32x128 = 1024 float4
            int u = tid + j * 256;
            int kk = u >> 5, c4 = u & 31;
            *(float4*)&Ws[kk][c4 * 4] = *(const float4*)&W[(k0 + kk) * 128 + c4 * 4];
        }
#pragma unroll
        for (int j = 0; j < 2; j++) {  // stage X chunk transposed: 64 rows x 32 k
            int u = tid + j * 256;     // 512 float4 units
            int r = u >> 3, kq = u & 7;
            int row = row0 + r;
            if (row > N - 1) row = N - 1;
            float4 v = *(const float4*)&in[(size_t)row * 128 + k0 + kq * 4];
            Xs[kq * 4 + 0][r] = v.x;
            Xs[kq * 4 + 1][r] = v.y;
            Xs[kq * 4 + 2][r] = v.z;
            Xs[kq * 4 + 3][r] = v.w;
        }
        __syncthreads();
#pragma unroll 8
        for (int kk = 0; kk < 32; kk++) {
            float4 xv = *(const float4*)&Xs[kk][tr * 4];
            float4 wa = *(const float4*)&Ws[kk][tc * 8];
            float4 wb = *(const float4*)&Ws[kk][tc * 8 + 4];
            float xr[4] = {xv.x, xv.y, xv.z, xv.w};
            float wc[8] = {wa.x, wa.y, wa.z, wa.w, wb.x, wb.y, wb.z, wb.w};
#pragma unroll
            for (int i = 0; i < 4; i++)
#pragma unroll
                for (int j = 0; j < 8; j++) acc[i][j] += xr[i] * wc[j];
        }
        __syncthreads();
    }
#pragma unroll
    for (int i = 0; i < 4; i++) {
        int row = row0 + tr * 4 + i;
        if (row < N) {
            float di = dinv[row];
            union {
                uint4 u;
                __half h[8];
            } pk;
#pragma unroll
            for (int j = 0; j < 8; j++) pk.h[j] = __float2half_rn(di * acc[i][j]);
            *(uint4*)&out[(size_t)row * 128 + tc * 8] = pk.u;
        }
    }
}

// one wave per node; half2 (2 cols) per lane; fp32 accumulate; 8-deep MLP unroll.
__global__ __launch_bounds__(256) void k_agg128h(const __half* __restrict__ hs,
                                                 const int* __restrict__ row_ptr,
                                                 const unsigned short* __restrict__ ss,
                                                 const float* __restrict__ dinv,
                                                 const float* __restrict__ bias, int N,
                                                 int do_relu, float* __restrict__ out) {
    int wid = threadIdx.x >> 6;
    int lane = threadIdx.x & 63;
    int node = blockIdx.x * 4 + wid;
    if (node >= N) return;
    const __half2* hp = (const __half2*)hs;  // row stride 64 half2
    float2 acc = __half22float2(hp[(size_t)node * 64 + lane]);  // self-loop term
    int s = row_ptr[node], e = row_ptr[node + 1];
    int i = s;
    for (; i + 8 <= e; i += 8) {
        int id[8];
#pragma unroll
        for (int u = 0; u < 8; u++) id[u] = __builtin_nontemporal_load(&ss[i + u]);
        float2 v[8];
#pragma unroll
        for (int u = 0; u < 8; u++) v[u] = __half22float2(hp[(size_t)id[u] * 64 + lane]);
        float sx0 = (v[0].x + v[1].x) + (v[2].x + v[3].x);
        float sx1 = (v[4].x + v[5].x) + (v[6].x + v[7].x);
        float sy0 = (v[0].y + v[1].y) + (v[2].y + v[3].y);
        float sy1 = (v[4].y + v[5].y) + (v[6].y + v[7].y);
        acc.x += sx0 + sx1;
        acc.y += sy0 + sy1;
    }
    for (; i < e; i++) {
        float2 v0 = __half22float2(hp[(size_t)ss[i] * 64 + lane]);
        acc.x += v0.x;
        acc.y += v0.y;
    }
    float di = dinv[node];
    int c = lane * 2;
    float2 b = *(const float2*)&bias[c];
    float ox = di * acc.x + b.x;
    float oy = di * acc.y + b.y;
    if (do_relu) {
        ox = fmaxf(ox, 0.f);
        oy = fmaxf(oy, 0.f);
    }
    vfloat2 o;
    o.x = ox;
    o.y = oy;
    __builtin_nontemporal_store(o, (vfloat2*)&out[(size_t)node * 128 + c]);
}

// heads: ths[n][j] = dinv[n] * sum_k h[n][k] * Wcat[k][j], Wcat = [W_age|W_sex|W_eth]
__global__ __launch_bounds__(256) void k_headgemm(const float* __restrict__ h,
                                                  const float* __restrict__ Wa,
                                                  const float* __restrict__ Wsx,
                                                  const float* __restrict__ We,
                                                  const float* __restrict__ dinv, int N,
                                                  float* __restrict__ ths) {
    __shared__ float Ws8[128][8];
    int tid = threadIdx.x;
#pragma unroll
    for (int j = 0; j < 4; j++) {
        int u = tid + j * 256;  // 1024 entries
        int k = u >> 3, c = u & 7;
        float v;
        if (c < 3) v = Wa[k * 3 + c];
        else if (c < 5) v = Wsx[k * 2 + (c - 3)];
        else v = We[k * 3 + (c - 5)];
        Ws8[k][c] = v;
    }
    __syncthreads();
    int node = blockIdx.x * 32 + (tid >> 3);
    int col = tid & 7;
    if (node >= N) return;
    const float* hr = &h[(size_t)node * 128];
    float acc = 0.f;
#pragma unroll 4
    for (int k = 0; k < 128; k += 4) {
        float4 hv = *(const float4*)&hr[k];
        acc += hv.x * Ws8[k][col] + hv.y * Ws8[k + 1][col] + hv.z * Ws8[k + 2][col] +
               hv.w * Ws8[k + 3][col];
    }
    ths[(size_t)node * 8 + col] = dinv[node] * acc;
}

__global__ __launch_bounds__(256) void k_agg8(const float* __restrict__ ths,
                                              const int* __restrict__ row_ptr,
                                              const unsigned short* __restrict__ ss,
                                              const float* __restrict__ dinv,
                                              const float* __restrict__ ba,
                                              const float* __restrict__ bs,
                                              const float* __restrict__ be, int N,
                                              float* __restrict__ outp) {
    int tid = threadIdx.x;
    int node = blockIdx.x * 32 + (tid >> 3);
    int j = tid & 7;
    if (node >= N) return;
    float acc = ths[(size_t)node * 8 + j];  // self
    int s = row_ptr[node], e = row_ptr[node + 1];
    for (int i = s; i < e; i++) {
        int sc = ss[i];
        acc += ths[(size_t)sc * 8 + j];
    }
    float bias = (j < 3) ? ba[j] : ((j < 5) ? bs[j - 3] : be[j - 5]);
    float v = dinv[node] * acc + bias;
    if (j < 3) outp[(size_t)node * 3 + j] = v;
    else if (j < 5) outp[(size_t)N * 3 + (size_t)node * 2 + (j - 3)] = v;
    else outp[(size_t)N * 5 + (size_t)node * 3 + (j - 5)] = v;
}

extern "C" void kernel_launch(void* const* d_in, const int* in_sizes, int n_in,
                              void* d_out, int out_size, void* d_ws, size_t ws_size,
                              hipStream_t stream) {
    const float* x = (const float*)d_in[0];
    const int* edge = (const int*)d_in[1];
    const float* W1 = (const float*)d_in[2];
    const float* b1 = (const float*)d_in[3];
    const float* W2 = (const float*)d_in[4];
    const float* b2 = (const float*)d_in[5];
    const float* Wa = (const float*)d_in[6];
    const float* ba = (const float*)d_in[7];
    const float* Wsx = (const float*)d_in[8];
    const float* bs = (const float*)d_in[9];
    const float* We = (const float*)d_in[10];
    const float* be = (const float*)d_in[11];

    int N = in_sizes[0] / 128;
    int E = in_sizes[1] / 2;
    const int* srcp = edge;
    const int* dstp = edge + E;
    int nbuk = (N + 127) >> 7;

    char* ws = (char*)d_ws;
    size_t off = 0;
    auto alloc = [&](size_t bytes) -> char* {
        char* p = ws + off;
        off += (bytes + 255) & ~(size_t)255;
        return p;
    };
    int* bcount = (int*)alloc((size_t)(nbuk + 1) * 4);
    int* bbase = (int*)alloc((size_t)(nbuk + 1) * 4);
    int* bcur = (int*)alloc((size_t)(nbuk + 1) * 4);
    int* row_ptr = (int*)alloc((size_t)(N + 1) * 4);
    float* dinv = (float*)alloc((size_t)N * 4);
    unsigned* bbuf = (unsigned*)alloc((size_t)E * 4);
    unsigned short* sorted = (unsigned short*)alloc((size_t)E * 2);
    __half* bufH = (__half*)alloc((size_t)N * 128 * 2);  // fp16 hs (gather operand)
    float* bufF = (float*)alloc((size_t)N * 128 * 4);    // fp32 agg output / gemm input
    float* ths = (float*)alloc((size_t)N * 8 * 4);

    int nbT = (E + 4095) / 4096;

    hipMemsetAsync(bcount, 0, (size_t)(nbuk + 1) * 4, stream);
    k_bhist<<<nbT, 256, 0, stream>>>(dstp, E, nbuk, bcount);
    k_bscan<<<1, 512, 0, stream>>>(bcount, nbuk, bbase, bcur);
    k_passA<<<nbT, 256, 0, stream>>>(srcp, dstp, E, nbuk, bcur, bbuf);
    k_passB<<<nbuk, 256, 0, stream>>>(bbuf, bbase, N, row_ptr, dinv, sorted);

    int gb = (N + 63) / 64;
    k_gemm_scale_h<<<gb, 256, 0, stream>>>(x, W1, dinv, N, bufH);
    k_agg128h<<<(N + 3) / 4, 256, 0, stream>>>(bufH, row_ptr, sorted, dinv, b1, N, 1, bufF);
    k_gemm_scale_h<<<gb, 256, 0, stream>>>(bufF, W2, dinv, N, bufH);
    k_agg128h<<<(N + 3) / 4, 256, 0, stream>>>(bufH, row_ptr, sorted, dinv, b2, N, 1, bufF);
    k_headgemm<<<(N + 31) / 32, 256, 0, stream>>>(bufF, Wa, Wsx, We, dinv, N, ths);
    k_agg8<<<(N + 31) / 32, 256, 0, stream>>>(ths, row_ptr, sorted, dinv, ba, bs, be, N,
                                              (float*)d_out);
}